// Round 6
// baseline (670.684 us; speedup 1.0000x reference)
//
#include <hip/hip_runtime.h>
#include <math.h>

#define RDIM 192
#define FDIM 28
#define PTS_PER_BLOCK 32   // gather kernel: 256 threads, 8 lanes per point

#define BSHIFT 3                         // 8-cell buckets
#define BDIM   (RDIM >> BSHIFT)          // 24
#define NBUCKET (BDIM * BDIM * BDIM)     // 13824
#define NSHARD  16                       // counter shards (anti-contention)
#define HTOT    (NBUCKET * NSHARD)       // 221184

// SH constants (match reference)
#define SH_C0  0.28209479177387814f
#define SH_C1  0.4886025119029199f
#define SH_C2  0.5462742152960396f
#define SH_C20 0.15769578262626154f
#define SH_C22 0.2731371076480198f

__device__ __forceinline__ void cell_of(float px, float py, float pz,
                                        int& x0, int& y0, int& z0) {
    const float A = (RDIM - 1) / 8.0f;   // 23.875
    const float B = (RDIM - 1) * 0.5f;   // 95.5
    const float RM1 = (float)(RDIM - 1);
    float cx = fminf(fmaxf(px * A + B, 0.0f), RM1);
    float cy = fminf(fmaxf(py * A + B, 0.0f), RM1);
    float cz = fminf(fmaxf(pz * A + B, 0.0f), RM1);
    x0 = (int)floorf(cx);
    y0 = (int)floorf(cy);
    z0 = (int)floorf(cz);
}

__device__ __forceinline__ int bucket_of(int x0, int y0, int z0) {
    return ((z0 >> BSHIFT) * BDIM + (y0 >> BSHIFT)) * BDIM + (x0 >> BSHIFT);
}

// shard by bits 8..11 of i: all 16 shards live across concurrently-resident waves
__device__ __forceinline__ int slot_of(int b, int i) {
    return b * NSHARD + ((i >> 8) & (NSHARD - 1));
}

// ---------------------------------------------------------------- zero hist
__global__ __launch_bounds__(256)
void zero_hist(int* __restrict__ hist) {
    int i = blockIdx.x * 256 + threadIdx.x;
    if (i < HTOT) hist[i] = 0;
}

// ---------------------------------------------------------------- histogram
__global__ __launch_bounds__(256)
void hist_kernel(const float* __restrict__ points, int* __restrict__ hist, int N) {
    int i = blockIdx.x * 256 + threadIdx.x;
    if (i >= N) return;
    float px = points[3 * i + 0];
    float py = points[3 * i + 1];
    float pz = points[3 * i + 2];
    int x0, y0, z0;
    cell_of(px, py, pz, x0, y0, z0);
    atomicAdd(&hist[slot_of(bucket_of(x0, y0, z0), i)], 1);
}

// ---------------------------------------------------------------- scan (1 block, 221184 entries)
#define SCAN_T 1024
#define SCAN_V (HTOT / SCAN_T)   // 216
__global__ __launch_bounds__(SCAN_T)
void scan_kernel(const int* __restrict__ hist, int* __restrict__ offs) {
    __shared__ int lds[SCAN_T];
    int t = threadIdx.x;
    int base = t * SCAN_V;
    int s = 0;
    for (int k = 0; k < SCAN_V; ++k) s += hist[base + k];
    lds[t] = s;
    __syncthreads();
    for (int off = 1; off < SCAN_T; off <<= 1) {
        int add = (t >= off) ? lds[t - off] : 0;
        __syncthreads();
        lds[t] += add;
        __syncthreads();
    }
    int excl = (t == 0) ? 0 : lds[t - 1];
    for (int k = 0; k < SCAN_V; ++k) {
        int h = hist[base + k];
        offs[base + k] = excl;
        excl += h;
    }
}

// ---------------------------------------------------------------- scatter (metadata only)
__global__ __launch_bounds__(256)
void scatter_kernel(const float* __restrict__ points, int* __restrict__ offs,
                    int* __restrict__ order, int N) {
    int i = blockIdx.x * 256 + threadIdx.x;
    if (i >= N) return;
    float px = points[3 * i + 0];
    float py = points[3 * i + 1];
    float pz = points[3 * i + 2];
    int x0, y0, z0;
    cell_of(px, py, pz, x0, y0, z0);
    int pos = atomicAdd(&offs[slot_of(bucket_of(x0, y0, z0), i)], 1);
    order[pos] = i;   // scattered 4B write
}

// ---------------------------------------------------------------- gather + shade (direct scattered out)
__global__ __launch_bounds__(256)
void plenoxel_fwd(const int* __restrict__ order,
                  const float* __restrict__ points,
                  const float* __restrict__ voxels,
                  float* __restrict__ out_rgb,    // N*3
                  float* __restrict__ out_sigma,  // N
                  int N)
{
    __shared__ float feats[PTS_PER_BLOCK][FDIM];  // 3.5 KB
    __shared__ float4 plds[PTS_PER_BLOCK];        // x,y,z, w=orig idx bits

    const int tid   = threadIdx.x;
    const int group = tid >> 3;   // 0..31 : point within block
    const int f     = tid & 7;    // 0..7  : feature-quad (7 idle for loads)
    const int p     = blockIdx.x * PTS_PER_BLOCK + group;

    if (p < N && f < 7) {
        int oi = order[p];                  // coalesced-ish (8 lanes same value)
        float px = points[3 * oi + 0];      // scattered 12B, points is L3-resident
        float py = points[3 * oi + 1];
        float pz = points[3 * oi + 2];

        if (f == 0) plds[group] = make_float4(px, py, pz, __int_as_float(oi));

        int x0, y0, z0;
        cell_of(px, py, pz, x0, y0, z0);
        const float A = (RDIM - 1) / 8.0f;
        const float B = (RDIM - 1) * 0.5f;
        const float RM1 = (float)(RDIM - 1);
        float cx = fminf(fmaxf(px * A + B, 0.0f), RM1);
        float cy = fminf(fmaxf(py * A + B, 0.0f), RM1);
        float cz = fminf(fmaxf(pz * A + B, 0.0f), RM1);
        float fx = cx - (float)x0, fy = cy - (float)y0, fz = cz - (float)z0;
        int x1 = min(x0 + 1, RDIM - 1);
        int y1 = min(y0 + 1, RDIM - 1);
        int z1 = min(z0 + 1, RDIM - 1);

        float gx = 1.0f - fx, gy = 1.0f - fy, gz = 1.0f - fz;

        float w000 = gz * gy * gx;
        float w001 = gz * gy * fx;
        float w010 = gz * fy * gx;
        float w011 = gz * fy * fx;
        float w100 = fz * gy * gx;
        float w101 = fz * gy * fx;
        float w110 = fz * fy * gx;
        float w111 = fz * fy * fx;

        int b000 = ((z0 * RDIM + y0) * RDIM + x0) * FDIM;
        int b001 = ((z0 * RDIM + y0) * RDIM + x1) * FDIM;
        int b010 = ((z0 * RDIM + y1) * RDIM + x0) * FDIM;
        int b011 = ((z0 * RDIM + y1) * RDIM + x1) * FDIM;
        int b100 = ((z1 * RDIM + y0) * RDIM + x0) * FDIM;
        int b101 = ((z1 * RDIM + y0) * RDIM + x1) * FDIM;
        int b110 = ((z1 * RDIM + y1) * RDIM + x0) * FDIM;
        int b111 = ((z1 * RDIM + y1) * RDIM + x1) * FDIM;

        const float4* __restrict__ src = (const float4*)voxels;

        float4 v0 = src[(b000 >> 2) + f];
        float4 v1 = src[(b001 >> 2) + f];
        float4 v2 = src[(b010 >> 2) + f];
        float4 v3 = src[(b011 >> 2) + f];
        float4 v4 = src[(b100 >> 2) + f];
        float4 v5 = src[(b101 >> 2) + f];
        float4 v6 = src[(b110 >> 2) + f];
        float4 v7 = src[(b111 >> 2) + f];

        float4 acc;
        acc.x = w000 * v0.x + w001 * v1.x + w010 * v2.x + w011 * v3.x
              + w100 * v4.x + w101 * v5.x + w110 * v6.x + w111 * v7.x;
        acc.y = w000 * v0.y + w001 * v1.y + w010 * v2.y + w011 * v3.y
              + w100 * v4.y + w101 * v5.y + w110 * v6.y + w111 * v7.y;
        acc.z = w000 * v0.z + w001 * v1.z + w010 * v2.z + w011 * v3.z
              + w100 * v4.z + w101 * v5.z + w110 * v6.z + w111 * v7.z;
        acc.w = w000 * v0.w + w001 * v1.w + w010 * v2.w + w011 * v3.w
              + w100 * v4.w + w101 * v5.w + w110 * v6.w + w111 * v7.w;

        *(float4*)&feats[group][4 * f] = acc;
    }

    __syncthreads();

    if (tid < PTS_PER_BLOCK) {
        int p2 = blockIdx.x * PTS_PER_BLOCK + tid;
        if (p2 < N) {
            float4 pt = plds[tid];
            float px = pt.x, py = pt.y, pz = pt.z;
            int oi = __float_as_int(pt.w);

            float inv = rsqrtf(px * px + py * py + pz * pz);
            float dx = px * inv, dy = py * inv, dz = pz * inv;

            float basis[9];
            basis[0] = SH_C0;
            basis[1] = SH_C1 * dy;
            basis[2] = SH_C1 * dz;
            basis[3] = SH_C1 * dx;
            basis[4] = SH_C2 * dx * dy;
            basis[5] = SH_C2 * dy * dz;
            basis[6] = SH_C20 * (3.0f * dz * dz - 1.0f);
            basis[7] = SH_C2 * dx * dz;
            basis[8] = SH_C22 * (dx * dx - dy * dy);

#pragma unroll
            for (int c = 0; c < 3; ++c) {
                float s = 0.0f;
#pragma unroll
                for (int j = 0; j < 9; ++j) {
                    s += feats[tid][1 + 9 * c + j] * basis[j];
                }
                out_rgb[3 * oi + c] = 1.0f / (1.0f + expf(-s));
            }

            float x = feats[tid][0];
            out_sigma[oi] = fmaxf(x, 0.0f) + log1pf(expf(-fabsf(x)));
        }
    }
}

extern "C" void kernel_launch(void* const* d_in, const int* in_sizes, int n_in,
                              void* d_out, int out_size, void* d_ws, size_t ws_size,
                              hipStream_t stream) {
    const float* points = (const float*)d_in[0];
    const float* voxels = (const float*)d_in[1];
    int N = in_sizes[0] / 3;

    float* out_rgb = (float*)d_out;              // N*3
    float* out_sigma = out_rgb + (size_t)3 * N;  // N

    // workspace layout (~10 MB of the ~3 GB ws)
    char* ws = (char*)d_ws;
    int* order = (int*)ws;                                 // N*4B
    int* hist  = (int*)(ws + (size_t)N * 4);               // HTOT*4B
    int* offs  = hist + HTOT;                              // HTOT*4B

    int pblocks = (N + 255) / 256;

    zero_hist<<<(HTOT + 255) / 256, 256, 0, stream>>>(hist);
    hist_kernel<<<pblocks, 256, 0, stream>>>(points, hist, N);
    scan_kernel<<<1, SCAN_T, 0, stream>>>(hist, offs);
    scatter_kernel<<<pblocks, 256, 0, stream>>>(points, offs, order, N);

    int gblocks = (N + PTS_PER_BLOCK - 1) / PTS_PER_BLOCK;
    plenoxel_fwd<<<gblocks, 256, 0, stream>>>(order, points, voxels, out_rgb, out_sigma, N);
}

// Round 7
// 350.494 us; speedup vs baseline: 1.9135x; 1.9135x over previous
//
#include <hip/hip_runtime.h>
#include <math.h>

#define RDIM 192
#define FDIM 28
#define PPB 64   // points per 256-thread block: 2 per 8-lane group

// SH constants (match reference)
#define SH_C0  0.28209479177387814f
#define SH_C1  0.4886025119029199f
#define SH_C2  0.5462742152960396f
#define SH_C20 0.15769578262626154f
#define SH_C22 0.2731371076480198f

__global__ __launch_bounds__(256)
void plenoxel_fwd(const float* __restrict__ points,
                  const float* __restrict__ voxels,
                  float* __restrict__ out_rgb,    // N*3
                  float* __restrict__ out_sigma,  // N
                  int N)
{
    __shared__ float feats[PPB][FDIM];   // 7 KB
    __shared__ float4 plds[PPB];         // 1 KB (x,y,z for epilogue)

    const int tid   = threadIdx.x;
    const int group = tid >> 3;   // 0..31
    const int f     = tid & 7;    // 0..7 (lane 7 idle for loads)
    const int pbase = blockIdx.x * PPB;
    const float4* __restrict__ src = (const float4*)voxels;

    const float A   = (RDIM - 1) / 8.0f;   // 23.875
    const float B   = (RDIM - 1) * 0.5f;   // 95.5
    const float RM1 = (float)(RDIM - 1);

    if (f < 7) {
        // ---- per-point setup macro: weights w<h>_*, float4-base a<h>_* ----
#define POINT_SETUP(h, PIDX)                                                  \
        const int p##h  = (PIDX);                                             \
        const int cp##h = min(p##h, N - 1);                                   \
        const float px##h = points[3 * cp##h + 0];                            \
        const float py##h = points[3 * cp##h + 1];                            \
        const float pz##h = points[3 * cp##h + 2];                            \
        if (f == 0) plds[group + 32 * h] =                                    \
            make_float4(px##h, py##h, pz##h, 0.0f);                           \
        float cx##h = fminf(fmaxf(px##h * A + B, 0.0f), RM1);                 \
        float cy##h = fminf(fmaxf(py##h * A + B, 0.0f), RM1);                 \
        float cz##h = fminf(fmaxf(pz##h * A + B, 0.0f), RM1);                 \
        float fcx##h = floorf(cx##h), fcy##h = floorf(cy##h),                 \
              fcz##h = floorf(cz##h);                                         \
        float fx##h = cx##h - fcx##h, fy##h = cy##h - fcy##h,                 \
              fz##h = cz##h - fcz##h;                                         \
        int x0##h = (int)fcx##h, y0##h = (int)fcy##h, z0##h = (int)fcz##h;    \
        int x1##h = min(x0##h + 1, RDIM - 1);                                 \
        int y1##h = min(y0##h + 1, RDIM - 1);                                 \
        int z1##h = min(z0##h + 1, RDIM - 1);                                 \
        float gx##h = 1.0f - fx##h, gy##h = 1.0f - fy##h,                     \
              gz##h = 1.0f - fz##h;                                           \
        float w##h##0 = gz##h * gy##h * gx##h;                                \
        float w##h##1 = gz##h * gy##h * fx##h;                                \
        float w##h##2 = gz##h * fy##h * gx##h;                                \
        float w##h##3 = gz##h * fy##h * fx##h;                                \
        float w##h##4 = fz##h * gy##h * gx##h;                                \
        float w##h##5 = fz##h * gy##h * fx##h;                                \
        float w##h##6 = fz##h * fy##h * gx##h;                                \
        float w##h##7 = fz##h * fy##h * fx##h;                                \
        int a##h##0 = ((((z0##h * RDIM + y0##h) * RDIM + x0##h) * FDIM) >> 2) + f; \
        int a##h##1 = ((((z0##h * RDIM + y0##h) * RDIM + x1##h) * FDIM) >> 2) + f; \
        int a##h##2 = ((((z0##h * RDIM + y1##h) * RDIM + x0##h) * FDIM) >> 2) + f; \
        int a##h##3 = ((((z0##h * RDIM + y1##h) * RDIM + x1##h) * FDIM) >> 2) + f; \
        int a##h##4 = ((((z1##h * RDIM + y0##h) * RDIM + x0##h) * FDIM) >> 2) + f; \
        int a##h##5 = ((((z1##h * RDIM + y0##h) * RDIM + x1##h) * FDIM) >> 2) + f; \
        int a##h##6 = ((((z1##h * RDIM + y1##h) * RDIM + x0##h) * FDIM) >> 2) + f; \
        int a##h##7 = ((((z1##h * RDIM + y1##h) * RDIM + x1##h) * FDIM) >> 2) + f;

        POINT_SETUP(0, pbase + group)
        POINT_SETUP(1, pbase + group + 32)
#undef POINT_SETUP

        // ---- issue all 16 independent 16B loads ----
        float4 v00 = src[a00]; float4 v01 = src[a01];
        float4 v02 = src[a02]; float4 v03 = src[a03];
        float4 v04 = src[a04]; float4 v05 = src[a05];
        float4 v06 = src[a06]; float4 v07 = src[a07];
        float4 v10 = src[a10]; float4 v11 = src[a11];
        float4 v12 = src[a12]; float4 v13 = src[a13];
        float4 v14 = src[a14]; float4 v15 = src[a15];
        float4 v16 = src[a16]; float4 v17 = src[a17];

        // ---- accumulate & stash ----
#define ACC_STORE(h, V0, V1, V2, V3, V4, V5, V6, V7, ROW)                     \
        {                                                                     \
            float4 acc;                                                       \
            acc.x = w##h##0 * V0.x + w##h##1 * V1.x + w##h##2 * V2.x          \
                  + w##h##3 * V3.x + w##h##4 * V4.x + w##h##5 * V5.x          \
                  + w##h##6 * V6.x + w##h##7 * V7.x;                          \
            acc.y = w##h##0 * V0.y + w##h##1 * V1.y + w##h##2 * V2.y          \
                  + w##h##3 * V3.y + w##h##4 * V4.y + w##h##5 * V5.y          \
                  + w##h##6 * V6.y + w##h##7 * V7.y;                          \
            acc.z = w##h##0 * V0.z + w##h##1 * V1.z + w##h##2 * V2.z          \
                  + w##h##3 * V3.z + w##h##4 * V4.z + w##h##5 * V5.z          \
                  + w##h##6 * V6.z + w##h##7 * V7.z;                          \
            acc.w = w##h##0 * V0.w + w##h##1 * V1.w + w##h##2 * V2.w          \
                  + w##h##3 * V3.w + w##h##4 * V4.w + w##h##5 * V5.w          \
                  + w##h##6 * V6.w + w##h##7 * V7.w;                          \
            *(float4*)&feats[ROW][4 * f] = acc;                               \
        }

        ACC_STORE(0, v00, v01, v02, v03, v04, v05, v06, v07, group)
        ACC_STORE(1, v10, v11, v12, v13, v14, v15, v16, v17, group + 32)
#undef ACC_STORE
    }

    __syncthreads();

    // ---- epilogue: one thread per point (64 of 256) ----
    if (tid < PPB) {
        int p2 = pbase + tid;
        if (p2 < N) {
            float4 pt = plds[tid];
            float px = pt.x, py = pt.y, pz = pt.z;

            float inv = rsqrtf(px * px + py * py + pz * pz);
            float dx = px * inv, dy = py * inv, dz = pz * inv;

            float basis[9];
            basis[0] = SH_C0;
            basis[1] = SH_C1 * dy;
            basis[2] = SH_C1 * dz;
            basis[3] = SH_C1 * dx;
            basis[4] = SH_C2 * dx * dy;
            basis[5] = SH_C2 * dy * dz;
            basis[6] = SH_C20 * (3.0f * dz * dz - 1.0f);
            basis[7] = SH_C2 * dx * dz;
            basis[8] = SH_C22 * (dx * dx - dy * dy);

#pragma unroll
            for (int c = 0; c < 3; ++c) {
                float s = 0.0f;
#pragma unroll
                for (int j = 0; j < 9; ++j) {
                    s += feats[tid][1 + 9 * c + j] * basis[j];
                }
                float r = 1.0f / (1.0f + expf(-s));
                __builtin_nontemporal_store(r, &out_rgb[3 * p2 + c]);
            }

            float x = feats[tid][0];
            float sig = fmaxf(x, 0.0f) + log1pf(expf(-fabsf(x)));
            __builtin_nontemporal_store(sig, &out_sigma[p2]);
        }
    }
}

extern "C" void kernel_launch(void* const* d_in, const int* in_sizes, int n_in,
                              void* d_out, int out_size, void* d_ws, size_t ws_size,
                              hipStream_t stream) {
    const float* points = (const float*)d_in[0];
    const float* voxels = (const float*)d_in[1];
    int N = in_sizes[0] / 3;

    float* out_rgb = (float*)d_out;              // N*3
    float* out_sigma = out_rgb + (size_t)3 * N;  // N

    int blocks = (N + PPB - 1) / PPB;
    plenoxel_fwd<<<blocks, 256, 0, stream>>>(points, voxels, out_rgb, out_sigma, N);
}